// Round 1
// baseline (4484.581 us; speedup 1.0000x reference)
//
#include <hip/hip_runtime.h>
#include <hip/hip_bf16.h>
#include <math.h>

// Problem constants
#define B_  2
#define N_  2048
#define D_  1024
#define H_  16
#define DH_ 64
// N_ = 2^11, DH_ = 2^6

// ---------------- GEMM: out = A[M,K] @ W[K,Nc] + bias ----------------
// mode 0: scatter output to [B,H,N,DH] (row r=b*N+n, col c=h*64+dh)
// mode 1: plain row-major [M,Nc]
#define BM 128
#define BN 128
#define BK 8
#define TM 8
#define TN 8

__global__ __launch_bounds__(256) void gemm_kernel(
    const float* __restrict__ A, const float* __restrict__ W,
    const float* __restrict__ bias, float* __restrict__ out,
    int M, int Nc, int K, int mode)
{
    __shared__ float As[BK][BM];
    __shared__ float Bs[BK][BN];

    const int tid = threadIdx.x;
    const int tx = tid & 15;       // 0..15
    const int ty = tid >> 4;       // 0..15
    const int rowBase = blockIdx.y * BM;
    const int colBase = blockIdx.x * BN;

    // A tile load: 128 rows x 8 cols, one float4 per thread
    const int arow = tid >> 1;          // 0..127
    const int acol = (tid & 1) * 4;     // 0 or 4
    // B tile load: 8 rows x 128 cols, one float4 per thread
    const int brow = tid >> 5;          // 0..7
    const int bcol = (tid & 31) * 4;    // 0..124

    float acc[TM][TN];
    #pragma unroll
    for (int i = 0; i < TM; ++i)
        #pragma unroll
        for (int j = 0; j < TN; ++j) acc[i][j] = 0.f;

    for (int k0 = 0; k0 < K; k0 += BK) {
        float4 av = *(const float4*)(A + (size_t)(rowBase + arow) * K + k0 + acol);
        As[acol + 0][arow] = av.x;
        As[acol + 1][arow] = av.y;
        As[acol + 2][arow] = av.z;
        As[acol + 3][arow] = av.w;
        float4 bv = *(const float4*)(W + (size_t)(k0 + brow) * Nc + colBase + bcol);
        *(float4*)(&Bs[brow][bcol]) = bv;
        __syncthreads();

        #pragma unroll
        for (int kk = 0; kk < BK; ++kk) {
            float rm[TM], rn[TN];
            #pragma unroll
            for (int t = 0; t < TM; ++t) rm[t] = As[kk][ty * TM + t];
            #pragma unroll
            for (int t = 0; t < TN; ++t) rn[t] = Bs[kk][tx * TN + t];
            #pragma unroll
            for (int a2 = 0; a2 < TM; ++a2)
                #pragma unroll
                for (int b2 = 0; b2 < TN; ++b2)
                    acc[a2][b2] += rm[a2] * rn[b2];
        }
        __syncthreads();
    }

    // epilogue
    #pragma unroll
    for (int a2 = 0; a2 < TM; ++a2) {
        const int r = rowBase + ty * TM + a2;
        #pragma unroll
        for (int b2 = 0; b2 < TN; ++b2) {
            const int c = colBase + tx * TN + b2;
            float v = acc[a2][b2] + bias[c];
            if (mode == 0) {
                // r = b*N + n ; c = h*64 + dh -> [B,H,N,DH]
                const int b  = r >> 11;        // /N_
                const int n  = r & (N_ - 1);
                const int h  = c >> 6;
                const int dh = c & 63;
                out[(((size_t)(b * H_ + h)) * N_ + n) * DH_ + dh] = v;
            } else {
                out[(size_t)r * Nc + c] = v;
            }
        }
    }
}

// ---------------- Attention: one block per (b,h,row i) ----------------
__global__ __launch_bounds__(256) void attn_kernel(
    const float* __restrict__ Q, const float* __restrict__ K,
    const float* __restrict__ V, float* __restrict__ Aout,
    float* __restrict__ Ypre)
{
    __shared__ float s_s[N_];      // scores -> exp values
    __shared__ float q_s[DH_];
    __shared__ float red[8];
    __shared__ float yred[4][DH_];

    const int bid = blockIdx.x;
    const int i  = bid & (N_ - 1);
    const int bh = bid >> 11;                 // b*H + h
    const size_t kvbase = (size_t)bh * N_ * DH_;
    const int tid = threadIdx.x;

    if (tid < DH_) q_s[tid] = Q[kvbase + (size_t)i * DH_ + tid];
    __syncthreads();

    // phase 1: scores s_j = (q . k_j) * scale for j <= i
    const float4* q4 = (const float4*)q_s;
    float mloc = -1e30f;
    for (int j = tid; j < N_; j += 256) {
        float sc = -1e30f;
        if (j <= i) {
            const float4* kp = (const float4*)(K + kvbase + (size_t)j * DH_);
            float dot = 0.f;
            #pragma unroll
            for (int t = 0; t < 16; ++t) {
                float4 qa = q4[t];
                float4 kb = kp[t];
                dot += qa.x * kb.x + qa.y * kb.y + qa.z * kb.z + qa.w * kb.w;
            }
            sc = dot * 0.125f;   // 1/sqrt(64)
        }
        s_s[j] = sc;
        mloc = fmaxf(mloc, sc);
    }
    // block max reduce
    #pragma unroll
    for (int off = 32; off > 0; off >>= 1)
        mloc = fmaxf(mloc, __shfl_down(mloc, off));
    if ((tid & 63) == 0) red[tid >> 6] = mloc;
    __syncthreads();
    if (tid == 0)
        red[4] = fmaxf(fmaxf(red[0], red[1]), fmaxf(red[2], red[3]));
    __syncthreads();
    const float m = red[4];

    // phase 2: exp + sum
    float sloc = 0.f;
    for (int j = tid; j < N_; j += 256) {
        float e = __expf(s_s[j] - m);   // -1e30 -> 0
        s_s[j] = e;
        sloc += e;
    }
    #pragma unroll
    for (int off = 32; off > 0; off >>= 1)
        sloc += __shfl_down(sloc, off);
    if ((tid & 63) == 0) red[tid >> 6] = sloc;
    __syncthreads();
    if (tid == 0)
        red[5] = red[0] + red[1] + red[2] + red[3];
    __syncthreads();
    const float inv = 1.0f / red[5];

    // write A row (normalized), float4 stores
    float4* arow = (float4*)(Aout + ((size_t)bh * N_ + i) * N_);
    for (int j4 = tid; j4 < N_ / 4; j4 += 256) {
        float4 v;
        v.x = s_s[j4 * 4 + 0] * inv;
        v.y = s_s[j4 * 4 + 1] * inv;
        v.z = s_s[j4 * 4 + 2] * inv;
        v.w = s_s[j4 * 4 + 3] * inv;
        arow[j4] = v;
    }

    // phase 3: y_d = inv * sum_j e_j * V[j][d]
    const int g = tid >> 6;      // group 0..3
    const int d = tid & 63;
    float acc = 0.f;
    for (int j = g; j <= i; j += 4)
        acc += s_s[j] * V[kvbase + (size_t)j * DH_ + d];
    yred[g][d] = acc;
    __syncthreads();
    if (tid < DH_) {
        float y = (yred[0][tid] + yred[1][tid] + yred[2][tid] + yred[3][tid]) * inv;
        const int b = bh >> 4;    // /H_
        const int h = bh & 15;
        Ypre[((size_t)b * N_ + i) * D_ + h * DH_ + tid] = y;
    }
}

extern "C" void kernel_launch(void* const* d_in, const int* in_sizes, int n_in,
                              void* d_out, int out_size, void* d_ws, size_t ws_size,
                              hipStream_t stream) {
    const float* x  = (const float*)d_in[0];
    // d_in[1] = mask (causal tril, hardcoded)
    const float* Wq = (const float*)d_in[2];
    const float* bq = (const float*)d_in[3];
    const float* Wk = (const float*)d_in[4];
    const float* bk = (const float*)d_in[5];
    const float* Wv = (const float*)d_in[6];
    const float* bv = (const float*)d_in[7];
    const float* Wp = (const float*)d_in[8];
    const float* bp = (const float*)d_in[9];

    float* out_y = (float*)d_out;                       // [B,N,D]
    float* out_A = out_y + (size_t)B_ * N_ * D_;        // [B,H,N,N]

    const size_t qkv_elems = (size_t)B_ * H_ * N_ * DH_;  // 4,194,304
    float* Q    = (float*)d_ws;
    float* K    = Q + qkv_elems;
    float* V    = K + qkv_elems;
    float* Ypre = V + qkv_elems;

    const int M = B_ * N_;   // 4096
    dim3 ggrid(D_ / BN, M / BM);   // (8, 32)

    gemm_kernel<<<ggrid, 256, 0, stream>>>(x, Wq, bq, Q, M, D_, D_, 0);
    gemm_kernel<<<ggrid, 256, 0, stream>>>(x, Wk, bk, K, M, D_, D_, 0);
    gemm_kernel<<<ggrid, 256, 0, stream>>>(x, Wv, bv, V, M, D_, D_, 0);

    attn_kernel<<<B_ * H_ * N_, 256, 0, stream>>>(Q, K, V, out_A, Ypre);

    gemm_kernel<<<ggrid, 256, 0, stream>>>(Ypre, Wp, bp, out_y, M, D_, D_, 1);
}

// Round 2
// 1485.330 us; speedup vs baseline: 3.0192x; 3.0192x over previous
//
#include <hip/hip_runtime.h>
#include <hip/hip_bf16.h>
#include <math.h>

// Problem constants
#define B_  2
#define N_  2048
#define D_  1024
#define H_  16
#define DH_ 64
#define QT  64          // query rows per block
#define NQT (N_/QT)     // 32 q-tiles

typedef __attribute__((ext_vector_type(8))) short bf16x8;
typedef __attribute__((ext_vector_type(4))) float f32x4;

// ---------------- GEMM: out = A[M,K] @ W[K,Nc] + bias ----------------
// mode 0: bf16 out scattered to [B,H,N,DH]   (Q, K)
// mode 1: fp32 out row-major [M,Nc]          (final projection)
// mode 2: bf16 out transposed  [B,H,DH,N]    (V^T)
#define BM 128
#define BN 128
#define BK 8
#define TM 8
#define TN 8

__global__ __launch_bounds__(256) void gemm_kernel(
    const float* __restrict__ A, const float* __restrict__ W,
    const float* __restrict__ bias, void* __restrict__ outv,
    int M, int Nc, int K, int mode)
{
    __shared__ float As[BK][BM];
    __shared__ float Bs[BK][BN];

    const int tid = threadIdx.x;
    const int tx = tid & 15;
    const int ty = tid >> 4;
    const int rowBase = blockIdx.y * BM;
    const int colBase = blockIdx.x * BN;

    const int arow = tid >> 1;
    const int acol = (tid & 1) * 4;
    const int brow = tid >> 5;
    const int bcol = (tid & 31) * 4;

    float acc[TM][TN];
    #pragma unroll
    for (int i = 0; i < TM; ++i)
        #pragma unroll
        for (int j = 0; j < TN; ++j) acc[i][j] = 0.f;

    for (int k0 = 0; k0 < K; k0 += BK) {
        float4 av = *(const float4*)(A + (size_t)(rowBase + arow) * K + k0 + acol);
        As[acol + 0][arow] = av.x;
        As[acol + 1][arow] = av.y;
        As[acol + 2][arow] = av.z;
        As[acol + 3][arow] = av.w;
        float4 bv = *(const float4*)(W + (size_t)(k0 + brow) * Nc + colBase + bcol);
        *(float4*)(&Bs[brow][bcol]) = bv;
        __syncthreads();

        #pragma unroll
        for (int kk = 0; kk < BK; ++kk) {
            float rm[TM], rn[TN];
            #pragma unroll
            for (int t = 0; t < TM; ++t) rm[t] = As[kk][ty * TM + t];
            #pragma unroll
            for (int t = 0; t < TN; ++t) rn[t] = Bs[kk][tx * TN + t];
            #pragma unroll
            for (int a2 = 0; a2 < TM; ++a2)
                #pragma unroll
                for (int b2 = 0; b2 < TN; ++b2)
                    acc[a2][b2] += rm[a2] * rn[b2];
        }
        __syncthreads();
    }

    #pragma unroll
    for (int a2 = 0; a2 < TM; ++a2) {
        const int r = rowBase + ty * TM + a2;
        #pragma unroll
        for (int b2 = 0; b2 < TN; ++b2) {
            const int c = colBase + tx * TN + b2;
            float v = acc[a2][b2] + bias[c];
            if (mode == 1) {
                ((float*)outv)[(size_t)r * Nc + c] = v;
            } else {
                const int b  = r >> 11;        // /N_
                const int n  = r & (N_ - 1);
                const int h  = c >> 6;
                const int dh = c & 63;
                __hip_bfloat16 hv = __float2bfloat16(v);
                if (mode == 0) {
                    ((__hip_bfloat16*)outv)[(((size_t)(b * H_ + h)) * N_ + n) * DH_ + dh] = hv;
                } else { // mode 2: V^T  [bh][dh][n]
                    ((__hip_bfloat16*)outv)[(((size_t)(b * H_ + h)) * DH_ + dh) * N_ + n] = hv;
                }
            }
        }
    }
}

// ---------------- MFMA flash-style attention ----------------
// Grid: NQT * (B_*H_) blocks, 256 threads (4 waves).
// Block handles one (b,h) and a 64-row q-tile; wave w owns rows w*16..w*16+15.
// Two passes over j-tiles (0..qt): pass1 online (m,l); pass2 A-write + P·V.
__global__ __launch_bounds__(256) void attn_mfma_kernel(
    const __hip_bfloat16* __restrict__ Qb, const __hip_bfloat16* __restrict__ Kb,
    const __hip_bfloat16* __restrict__ Vtb, float* __restrict__ Aout,
    float* __restrict__ Ypre)
{
    __shared__ short p_lds[4][16][72];   // per-wave P tile, bf16, padded (+8)

    const int tid  = threadIdx.x;
    const int w    = tid >> 6;
    const int lane = tid & 63;
    const int quad = lane >> 4;
    const int col  = lane & 15;

    const int bid = blockIdx.x;
    const int bh  = bid & 31;                  // b*H + h
    const int qt  = (NQT - 1) - (bid >> 5);    // heaviest tiles dispatched first
    const int qbase = qt * QT;
    const size_t kvbase = (size_t)bh * N_ * DH_;

    const short* Qs = (const short*)Qb + kvbase;
    const short* Ks = (const short*)Kb + kvbase;
    const short* Vs = (const short*)Vtb + kvbase;

    // persistent Q A-fragments (rows w*16+col, k-chunks 0..31 / 32..63)
    const short* qrow = Qs + (size_t)(qbase + w * 16 + col) * DH_ + quad * 8;
    const bf16x8 qf0 = *(const bf16x8*)(qrow);
    const bf16x8 qf1 = *(const bf16x8*)(qrow + 32);

    const int mrow_l = w * 16 + quad * 4;   // local row (reg 0)
    const int mrow_g = qbase + mrow_l;      // global query row (reg 0)

    float mrun[4] = {-1e30f, -1e30f, -1e30f, -1e30f};
    float lrun[4] = {0.f, 0.f, 0.f, 0.f};

    const int njt = qt + 1;

    // ---------------- pass 1: running max & denom ----------------
    for (int jt = 0; jt < njt; ++jt) {
        const int jbase = jt * QT;
        f32x4 s[4];
        #pragma unroll
        for (int nt = 0; nt < 4; ++nt) {
            const short* krow = Ks + (size_t)(jbase + nt * 16 + col) * DH_ + quad * 8;
            bf16x8 k0 = *(const bf16x8*)(krow);
            bf16x8 k1 = *(const bf16x8*)(krow + 32);
            f32x4 c = {0.f, 0.f, 0.f, 0.f};
            c = __builtin_amdgcn_mfma_f32_16x16x32_bf16(qf0, k0, c, 0, 0, 0);
            c = __builtin_amdgcn_mfma_f32_16x16x32_bf16(qf1, k1, c, 0, 0, 0);
            s[nt] = c;
        }
        const bool diag = (jt == qt);
        #pragma unroll
        for (int nt = 0; nt < 4; ++nt) {
            const int n_g = jbase + nt * 16 + col;
            #pragma unroll
            for (int r = 0; r < 4; ++r) {
                float v = s[nt][r] * 0.125f;
                if (diag && (n_g > mrow_g + r)) v = -1e30f;
                s[nt][r] = v;
            }
        }
        #pragma unroll
        for (int r = 0; r < 4; ++r) {
            float tmax = fmaxf(fmaxf(s[0][r], s[1][r]), fmaxf(s[2][r], s[3][r]));
            #pragma unroll
            for (int off = 1; off < 16; off <<= 1)
                tmax = fmaxf(tmax, __shfl_xor(tmax, off));
            float mnew = fmaxf(mrun[r], tmax);
            float psum = __expf(s[0][r] - mnew) + __expf(s[1][r] - mnew)
                       + __expf(s[2][r] - mnew) + __expf(s[3][r] - mnew);
            #pragma unroll
            for (int off = 1; off < 16; off <<= 1)
                psum += __shfl_xor(psum, off);
            lrun[r] = lrun[r] * __expf(mrun[r] - mnew) + psum;
            mrun[r] = mnew;
        }
    }

    float invl[4];
    #pragma unroll
    for (int r = 0; r < 4; ++r) invl[r] = 1.0f / lrun[r];

    f32x4 yacc[4] = {{0.f,0.f,0.f,0.f},{0.f,0.f,0.f,0.f},{0.f,0.f,0.f,0.f},{0.f,0.f,0.f,0.f}};

    // ---------------- pass 2: A write + P·V ----------------
    for (int jt = 0; jt < njt; ++jt) {
        const int jbase = jt * QT;
        f32x4 s[4];
        #pragma unroll
        for (int nt = 0; nt < 4; ++nt) {
            const short* krow = Ks + (size_t)(jbase + nt * 16 + col) * DH_ + quad * 8;
            bf16x8 k0 = *(const bf16x8*)(krow);
            bf16x8 k1 = *(const bf16x8*)(krow + 32);
            f32x4 c = {0.f, 0.f, 0.f, 0.f};
            c = __builtin_amdgcn_mfma_f32_16x16x32_bf16(qf0, k0, c, 0, 0, 0);
            c = __builtin_amdgcn_mfma_f32_16x16x32_bf16(qf1, k1, c, 0, 0, 0);
            s[nt] = c;
        }
        const bool diag = (jt == qt);
        #pragma unroll
        for (int nt = 0; nt < 4; ++nt) {
            const int n_g = jbase + nt * 16 + col;
            #pragma unroll
            for (int r = 0; r < 4; ++r) {
                float v = s[nt][r] * 0.125f;
                if (diag && (n_g > mrow_g + r)) v = -1e30f;
                float p = __expf(v - mrun[r]);           // unnormalized prob
                // write normalized A
                Aout[((size_t)bh * N_ + (mrow_g + r)) * N_ + n_g] = p * invl[r];
                // stash bf16 p for the PV MFMA (wave-private tile)
                __hip_bfloat16 hp = __float2bfloat16(p);
                p_lds[w][quad * 4 + r][nt * 16 + col] = *(short*)&hp;
            }
        }
        // wave-private LDS round-trip: C-layout -> A-operand layout
        bf16x8 pa0 = *(const bf16x8*)&p_lds[w][col][quad * 8];
        bf16x8 pa1 = *(const bf16x8*)&p_lds[w][col][32 + quad * 8];
        #pragma unroll
        for (int dt = 0; dt < 4; ++dt) {
            const short* vrow = Vs + (size_t)(dt * 16 + col) * N_ + jbase + quad * 8;
            bf16x8 v0 = *(const bf16x8*)(vrow);
            bf16x8 v1 = *(const bf16x8*)(vrow + 32);
            yacc[dt] = __builtin_amdgcn_mfma_f32_16x16x32_bf16(pa0, v0, yacc[dt], 0, 0, 0);
            yacc[dt] = __builtin_amdgcn_mfma_f32_16x16x32_bf16(pa1, v1, yacc[dt], 0, 0, 0);
        }
    }

    // Y epilogue: gather heads back to [B,N,D]
    const int b = bh >> 4, h = bh & 15;
    #pragma unroll
    for (int dt = 0; dt < 4; ++dt)
        #pragma unroll
        for (int r = 0; r < 4; ++r)
            Ypre[((size_t)b * N_ + mrow_g + r) * D_ + h * DH_ + dt * 16 + col]
                = yacc[dt][r] * invl[r];

    // zero-fill strictly-upper A tiles for these 64 rows (coalesced)
    float4 z; z.x = 0.f; z.y = 0.f; z.z = 0.f; z.w = 0.f;
    for (int r = 0; r < QT; ++r) {
        float4* row = (float4*)(Aout + ((size_t)bh * N_ + qbase + r) * N_);
        for (int c4 = (qt + 1) * (QT / 4) + tid; c4 < N_ / 4; c4 += 256)
            row[c4] = z;
    }
}

extern "C" void kernel_launch(void* const* d_in, const int* in_sizes, int n_in,
                              void* d_out, int out_size, void* d_ws, size_t ws_size,
                              hipStream_t stream) {
    const float* x  = (const float*)d_in[0];
    const float* Wq = (const float*)d_in[2];
    const float* bq = (const float*)d_in[3];
    const float* Wk = (const float*)d_in[4];
    const float* bk = (const float*)d_in[5];
    const float* Wv = (const float*)d_in[6];
    const float* bv = (const float*)d_in[7];
    const float* Wp = (const float*)d_in[8];
    const float* bp = (const float*)d_in[9];

    float* out_y = (float*)d_out;                       // [B,N,D]
    float* out_A = out_y + (size_t)B_ * N_ * D_;        // [B,H,N,N]

    const size_t qkv_elems = (size_t)B_ * H_ * N_ * DH_;   // 4,194,304
    __hip_bfloat16* Q  = (__hip_bfloat16*)d_ws;
    __hip_bfloat16* K  = Q + qkv_elems;
    __hip_bfloat16* Vt = K + qkv_elems;
    float* Ypre = (float*)(Vt + qkv_elems);

    const int M = B_ * N_;   // 4096
    dim3 ggrid(D_ / BN, M / BM);   // (8, 32)

    gemm_kernel<<<ggrid, 256, 0, stream>>>(x, Wq, bq, Q,  M, D_, D_, 0);
    gemm_kernel<<<ggrid, 256, 0, stream>>>(x, Wk, bk, K,  M, D_, D_, 0);
    gemm_kernel<<<ggrid, 256, 0, stream>>>(x, Wv, bv, Vt, M, D_, D_, 2);

    attn_mfma_kernel<<<NQT * B_ * H_, 256, 0, stream>>>(Q, K, Vt, out_A, Ypre);

    gemm_kernel<<<ggrid, 256, 0, stream>>>(Ypre, Wp, bp, out_y, M, D_, D_, 1);
}

// Round 3
// 871.992 us; speedup vs baseline: 5.1429x; 1.7034x over previous
//
#include <hip/hip_runtime.h>
#include <hip/hip_bf16.h>
#include <math.h>

// Problem constants
#define B_  2
#define N_  2048
#define D_  1024
#define H_  16
#define DH_ 64
#define QT  64          // query rows per block (attention)
#define NQT (N_/QT)     // 32 q-tiles

typedef __attribute__((ext_vector_type(8))) short bf16x8;
typedef __attribute__((ext_vector_type(4))) float f32x4;

#define ASYNC16(g, l) __builtin_amdgcn_global_load_lds( \
    (const __attribute__((address_space(1))) void*)(g), \
    (__attribute__((address_space(3))) void*)(l), 16, 0, 0)

__device__ __forceinline__ short f2bf(float f) {
    __hip_bfloat16 h = __float2bfloat16(f);
    return *(short*)&h;
}

// ---------------- cast x fp32 -> bf16 ----------------
__global__ __launch_bounds__(256) void cast_kernel(
    const float* __restrict__ in, short* __restrict__ out)
{
    const int i = (blockIdx.x * 256 + threadIdx.x) * 8;
    float4 a = *(const float4*)(in + i);
    float4 b = *(const float4*)(in + i + 4);
    bf16x8 o;
    o[0] = f2bf(a.x); o[1] = f2bf(a.y); o[2] = f2bf(a.z); o[3] = f2bf(a.w);
    o[4] = f2bf(b.x); o[5] = f2bf(b.y); o[6] = f2bf(b.z); o[7] = f2bf(b.w);
    *(bf16x8*)(out + i) = o;
}

// ---------------- transpose+cast W[K,Nc] fp32 -> Wt[Nc,K] bf16 ----------------
__global__ __launch_bounds__(256) void tc_kernel(
    const float* __restrict__ in, short* __restrict__ out, int K, int Nc)
{
    __shared__ float t[64][65];
    const int tid = threadIdx.x;
    const int k0 = blockIdx.y * 64, n0 = blockIdx.x * 64;
    #pragma unroll
    for (int p = 0; p < 4; ++p) {
        const int r = p * 16 + (tid >> 4);
        const int c = (tid & 15) * 4;
        float4 v = *(const float4*)(in + (size_t)(k0 + r) * Nc + n0 + c);
        t[r][c] = v.x; t[r][c+1] = v.y; t[r][c+2] = v.z; t[r][c+3] = v.w;
    }
    __syncthreads();
    #pragma unroll
    for (int p = 0; p < 4; ++p) {
        const int n = p * 16 + (tid >> 4);
        const int c = (tid & 15) * 4;     // k within tile
        ushort4 o;
        o.x = (unsigned short)f2bf(t[c + 0][n]);
        o.y = (unsigned short)f2bf(t[c + 1][n]);
        o.z = (unsigned short)f2bf(t[c + 2][n]);
        o.w = (unsigned short)f2bf(t[c + 3][n]);
        *(ushort4*)(out + (size_t)(n0 + n) * K + k0 + c) = o;
    }
}

// ---------------- MFMA GEMM: C = A[M,K]bf16 @ Bt[Nc,K]bf16^T + bias ----------------
// mode 0: bf16 out scattered to [B,H,N,DH]   (Q, K)
// mode 1: fp32 out row-major [M,Nc]          (final projection)
// mode 2: bf16 out transposed  [B,H,DH,N]    (V^T)
__global__ __launch_bounds__(256) void gemm_mfma(
    const short* __restrict__ A, const short* __restrict__ Bt,
    const float* __restrict__ bias, void* __restrict__ outv,
    int M, int Nc, int K, int mode)
{
    __shared__ short As[128 * 64];
    __shared__ short Bs[128 * 64];

    const int tid  = threadIdx.x;
    const int w    = tid >> 6;
    const int lane = tid & 63;
    const int quad = lane >> 4;
    const int col  = lane & 15;
    const int wr   = (w >> 1) * 64;     // wave row quadrant
    const int wc   = (w & 1) * 64;      // wave col quadrant

    const int rowBase = blockIdx.y * 128;
    const int colBase = blockIdx.x * 128;

    // staging addressing: per issue i, 32 rows; thread covers row i*32+(tid>>3),
    // cols (tid&7)*8 .. +7 ; LDS offset = i*32*64 + tid*8 (elements)
    const int srow = tid >> 3;
    const int scol = (tid & 7) * 8;

    f32x4 acc[4][4];
    #pragma unroll
    for (int i = 0; i < 4; ++i)
        #pragma unroll
        for (int j = 0; j < 4; ++j) acc[i][j] = (f32x4){0.f, 0.f, 0.f, 0.f};

    for (int k0 = 0; k0 < K; k0 += 64) {
        __syncthreads();
        #pragma unroll
        for (int i = 0; i < 4; ++i) {
            ASYNC16(A + (size_t)(rowBase + i * 32 + srow) * K + k0 + scol,
                    As + i * 2048 + tid * 8);
            ASYNC16(Bt + (size_t)(colBase + i * 32 + srow) * K + k0 + scol,
                    Bs + i * 2048 + tid * 8);
        }
        __syncthreads();

        #pragma unroll
        for (int kk = 0; kk < 2; ++kk) {
            bf16x8 af[4], bf[4];
            #pragma unroll
            for (int mt = 0; mt < 4; ++mt)
                af[mt] = *(const bf16x8*)&As[(wr + mt * 16 + col) * 64 + kk * 32 + quad * 8];
            #pragma unroll
            for (int nt = 0; nt < 4; ++nt)
                bf[nt] = *(const bf16x8*)&Bs[(wc + nt * 16 + col) * 64 + kk * 32 + quad * 8];
            #pragma unroll
            for (int mt = 0; mt < 4; ++mt)
                #pragma unroll
                for (int nt = 0; nt < 4; ++nt)
                    acc[mt][nt] = __builtin_amdgcn_mfma_f32_16x16x32_bf16(
                        af[mt], bf[nt], acc[mt][nt], 0, 0, 0);
        }
    }

    // epilogue: C row = rowBase+wr+mt*16+quad*4+r ; col = colBase+wc+nt*16+col
    #pragma unroll
    for (int mt = 0; mt < 4; ++mt) {
        #pragma unroll
        for (int r = 0; r < 4; ++r) {
            const int rr = rowBase + wr + mt * 16 + quad * 4 + r;
            #pragma unroll
            for (int nt = 0; nt < 4; ++nt) {
                const int cc = colBase + wc + nt * 16 + col;
                float v = acc[mt][nt][r] + bias[cc];
                if (mode == 1) {
                    ((float*)outv)[(size_t)rr * Nc + cc] = v;
                } else {
                    const int b  = rr >> 11;       // /N_
                    const int n  = rr & (N_ - 1);
                    const int h  = cc >> 6;
                    const int dh = cc & 63;
                    short hv = f2bf(v);
                    if (mode == 0)
                        ((short*)outv)[(((size_t)(b * H_ + h)) * N_ + n) * DH_ + dh] = hv;
                    else   // mode 2: V^T [bh][dh][n]
                        ((short*)outv)[(((size_t)(b * H_ + h)) * DH_ + dh) * N_ + n] = hv;
                }
            }
        }
    }
}

// ---------------- MFMA flash-style attention ----------------
__global__ __launch_bounds__(256) void attn_mfma_kernel(
    const __hip_bfloat16* __restrict__ Qb, const __hip_bfloat16* __restrict__ Kb,
    const __hip_bfloat16* __restrict__ Vtb, float* __restrict__ Aout,
    short* __restrict__ Ypre)
{
    __shared__ short p_lds[4][16][72];   // per-wave P tile, bf16, padded

    const int tid  = threadIdx.x;
    const int w    = tid >> 6;
    const int lane = tid & 63;
    const int quad = lane >> 4;
    const int col  = lane & 15;

    const int bid = blockIdx.x;
    const int bh  = bid & 31;                  // b*H + h
    const int qt  = (NQT - 1) - (bid >> 5);    // heaviest tiles first
    const int qbase = qt * QT;
    const size_t kvbase = (size_t)bh * N_ * DH_;

    const short* Qs = (const short*)Qb + kvbase;
    const short* Ks = (const short*)Kb + kvbase;
    const short* Vs = (const short*)Vtb + kvbase;

    const short* qrow = Qs + (size_t)(qbase + w * 16 + col) * DH_ + quad * 8;
    const bf16x8 qf0 = *(const bf16x8*)(qrow);
    const bf16x8 qf1 = *(const bf16x8*)(qrow + 32);

    const int mrow_g = qbase + w * 16 + quad * 4;   // global query row (reg 0)

    float mrun[4] = {-1e30f, -1e30f, -1e30f, -1e30f};
    float lrun[4] = {0.f, 0.f, 0.f, 0.f};

    const int njt = qt + 1;

    // pass 1: running max & denom
    for (int jt = 0; jt < njt; ++jt) {
        const int jbase = jt * QT;
        f32x4 s[4];
        #pragma unroll
        for (int nt = 0; nt < 4; ++nt) {
            const short* krow = Ks + (size_t)(jbase + nt * 16 + col) * DH_ + quad * 8;
            bf16x8 k0 = *(const bf16x8*)(krow);
            bf16x8 k1 = *(const bf16x8*)(krow + 32);
            f32x4 c = {0.f, 0.f, 0.f, 0.f};
            c = __builtin_amdgcn_mfma_f32_16x16x32_bf16(qf0, k0, c, 0, 0, 0);
            c = __builtin_amdgcn_mfma_f32_16x16x32_bf16(qf1, k1, c, 0, 0, 0);
            s[nt] = c;
        }
        const bool diag = (jt == qt);
        #pragma unroll
        for (int nt = 0; nt < 4; ++nt) {
            const int n_g = jbase + nt * 16 + col;
            #pragma unroll
            for (int r = 0; r < 4; ++r) {
                float v = s[nt][r] * 0.125f;
                if (diag && (n_g > mrow_g + r)) v = -1e30f;
                s[nt][r] = v;
            }
        }
        #pragma unroll
        for (int r = 0; r < 4; ++r) {
            float tmax = fmaxf(fmaxf(s[0][r], s[1][r]), fmaxf(s[2][r], s[3][r]));
            #pragma unroll
            for (int off = 1; off < 16; off <<= 1)
                tmax = fmaxf(tmax, __shfl_xor(tmax, off));
            float mnew = fmaxf(mrun[r], tmax);
            float psum = __expf(s[0][r] - mnew) + __expf(s[1][r] - mnew)
                       + __expf(s[2][r] - mnew) + __expf(s[3][r] - mnew);
            #pragma unroll
            for (int off = 1; off < 16; off <<= 1)
                psum += __shfl_xor(psum, off);
            lrun[r] = lrun[r] * __expf(mrun[r] - mnew) + psum;
            mrun[r] = mnew;
        }
    }

    float invl[4];
    #pragma unroll
    for (int r = 0; r < 4; ++r) invl[r] = 1.0f / lrun[r];

    f32x4 yacc[4] = {{0.f,0.f,0.f,0.f},{0.f,0.f,0.f,0.f},{0.f,0.f,0.f,0.f},{0.f,0.f,0.f,0.f}};

    // pass 2: A write + P·V
    for (int jt = 0; jt < njt; ++jt) {
        const int jbase = jt * QT;
        f32x4 s[4];
        #pragma unroll
        for (int nt = 0; nt < 4; ++nt) {
            const short* krow = Ks + (size_t)(jbase + nt * 16 + col) * DH_ + quad * 8;
            bf16x8 k0 = *(const bf16x8*)(krow);
            bf16x8 k1 = *(const bf16x8*)(krow + 32);
            f32x4 c = {0.f, 0.f, 0.f, 0.f};
            c = __builtin_amdgcn_mfma_f32_16x16x32_bf16(qf0, k0, c, 0, 0, 0);
            c = __builtin_amdgcn_mfma_f32_16x16x32_bf16(qf1, k1, c, 0, 0, 0);
            s[nt] = c;
        }
        const bool diag = (jt == qt);
        #pragma unroll
        for (int nt = 0; nt < 4; ++nt) {
            const int n_g = jbase + nt * 16 + col;
            #pragma unroll
            for (int r = 0; r < 4; ++r) {
                float v = s[nt][r] * 0.125f;
                if (diag && (n_g > mrow_g + r)) v = -1e30f;
                float p = __expf(v - mrun[r]);
                Aout[((size_t)bh * N_ + (mrow_g + r)) * N_ + n_g] = p * invl[r];
                p_lds[w][quad * 4 + r][nt * 16 + col] = f2bf(p);
            }
        }
        bf16x8 pa0 = *(const bf16x8*)&p_lds[w][col][quad * 8];
        bf16x8 pa1 = *(const bf16x8*)&p_lds[w][col][32 + quad * 8];
        #pragma unroll
        for (int dt = 0; dt < 4; ++dt) {
            const short* vrow = Vs + (size_t)(dt * 16 + col) * N_ + jbase + quad * 8;
            bf16x8 v0 = *(const bf16x8*)(vrow);
            bf16x8 v1 = *(const bf16x8*)(vrow + 32);
            yacc[dt] = __builtin_amdgcn_mfma_f32_16x16x32_bf16(pa0, v0, yacc[dt], 0, 0, 0);
            yacc[dt] = __builtin_amdgcn_mfma_f32_16x16x32_bf16(pa1, v1, yacc[dt], 0, 0, 0);
        }
    }

    // Y epilogue -> bf16 Ypre [B,N,D]
    const int b = bh >> 4, h = bh & 15;
    #pragma unroll
    for (int dt = 0; dt < 4; ++dt)
        #pragma unroll
        for (int r = 0; r < 4; ++r)
            Ypre[((size_t)b * N_ + mrow_g + r) * D_ + h * DH_ + dt * 16 + col]
                = f2bf(yacc[dt][r] * invl[r]);

    // zero-fill strictly-upper A tiles for these 64 rows
    float4 z; z.x = 0.f; z.y = 0.f; z.z = 0.f; z.w = 0.f;
    for (int r = 0; r < QT; ++r) {
        float4* row = (float4*)(Aout + ((size_t)bh * N_ + qbase + r) * N_);
        for (int c4 = (qt + 1) * (QT / 4) + tid; c4 < N_ / 4; c4 += 256)
            row[c4] = z;
    }
}

extern "C" void kernel_launch(void* const* d_in, const int* in_sizes, int n_in,
                              void* d_out, int out_size, void* d_ws, size_t ws_size,
                              hipStream_t stream) {
    const float* x  = (const float*)d_in[0];
    const float* Wq = (const float*)d_in[2];
    const float* bq = (const float*)d_in[3];
    const float* Wk = (const float*)d_in[4];
    const float* bk = (const float*)d_in[5];
    const float* Wv = (const float*)d_in[6];
    const float* bv = (const float*)d_in[7];
    const float* Wp = (const float*)d_in[8];
    const float* bp = (const float*)d_in[9];

    float* out_y = (float*)d_out;                       // [B,N,D]
    float* out_A = out_y + (size_t)B_ * N_ * D_;        // [B,H,N,N]

    const size_t qkv = (size_t)B_ * H_ * N_ * DH_;      // 4,194,304
    const size_t wsz = (size_t)D_ * D_;                 // 1,048,576
    short* Q    = (short*)d_ws;          // bf16
    short* K    = Q + qkv;
    short* Vt   = K + qkv;
    short* xb   = Vt + qkv;              // bf16 x  [M,K]
    short* Ypre = xb + qkv;              // bf16    [M,D]
    short* Wqt  = Ypre + qkv;            // bf16 Wt [N,K]
    short* Wkt  = Wqt + wsz;
    short* Wvt  = Wkt + wsz;
    short* Wpt  = Wvt + wsz;

    const int M = B_ * N_;               // 4096
    dim3 ggrid(D_ / 128, M / 128);       // (8, 32)
    dim3 tgrid(D_ / 64, D_ / 64);        // (16, 16)

    cast_kernel<<<(int)(qkv / (256 * 8)), 256, 0, stream>>>(x, xb);
    tc_kernel<<<tgrid, 256, 0, stream>>>(Wq, Wqt, D_, D_);
    tc_kernel<<<tgrid, 256, 0, stream>>>(Wk, Wkt, D_, D_);
    tc_kernel<<<tgrid, 256, 0, stream>>>(Wv, Wvt, D_, D_);
    tc_kernel<<<tgrid, 256, 0, stream>>>(Wp, Wpt, D_, D_);

    gemm_mfma<<<ggrid, 256, 0, stream>>>(xb, Wqt, bq, Q,  M, D_, D_, 0);
    gemm_mfma<<<ggrid, 256, 0, stream>>>(xb, Wkt, bk, K,  M, D_, D_, 0);
    gemm_mfma<<<ggrid, 256, 0, stream>>>(xb, Wvt, bv, Vt, M, D_, D_, 2);

    attn_mfma_kernel<<<NQT * B_ * H_, 256, 0, stream>>>(
        (const __hip_bfloat16*)Q, (const __hip_bfloat16*)K,
        (const __hip_bfloat16*)Vt, out_A, Ypre);

    gemm_mfma<<<ggrid, 256, 0, stream>>>(Ypre, Wpt, bp, out_y, M, D_, D_, 1);
}